// Round 1
// 13060.570 us; speedup vs baseline: 1.1245x; 1.1245x over previous
//
#include <hip/hip_runtime.h>
#include <hip/hip_bf16.h>

#define B_SZ   2048
#define T_SZ   256
#define EMB    128
#define NH     256
#define NCLASS 32000

typedef __bf16 bf16;
typedef __bf16 bf16x8 __attribute__((ext_vector_type(8)));
typedef __bf16 bf16x4 __attribute__((ext_vector_type(4)));
typedef float  f32x4  __attribute__((ext_vector_type(4)));

__device__ __forceinline__ float sigf(float x)      { return 1.0f / (1.0f + __expf(-x)); }
__device__ __forceinline__ float tanhfast(float x)  { return 2.0f / (1.0f + __expf(-2.0f * x)) - 1.0f; }

struct GatePtrs {
    const float* U1[4];  // [EMB][NH]
    const float* V1[4];  // [NH][NH]
    const float* U2[4];  // [NH][NH]
    const float* V2[4];  // [NH][NH]
};

// Gate-column layout: gc = nhgrp*64 + gate*16 + c ; nh = nhgrp*16 + c ; gate 0=i,1=f,2=c,3=o
// Wt1[gc][k] k in [0,384): k<128 -> U_g1[k][nh], else V_g1[k-128][nh]
__global__ void prep_w1(GatePtrs gp, bf16* __restrict__ Wt1) {
    int gc = blockIdx.x;          // 0..1023
    int k  = threadIdx.x;         // 0..383
    int g  = (gc >> 4) & 3;
    int nh = ((gc >> 6) << 4) | (gc & 15);
    float v = (k < EMB) ? gp.U1[g][k * NH + nh] : gp.V1[g][(k - EMB) * NH + nh];
    Wt1[gc * 384 + k] = (bf16)v;
}

// Wt2[gc][k] k in [0,512): k<256 -> U_g2[k][nh] (h1n), else V_g2[k-256][nh] (h2)
__global__ void prep_w2(GatePtrs gp, bf16* __restrict__ Wt2) {
    int gc = blockIdx.x;
    int k  = threadIdx.x;         // 0..511
    int g  = (gc >> 4) & 3;
    int nh = ((gc >> 6) << 4) | (gc & 15);
    float v = (k < NH) ? gp.U2[g][k * NH + nh] : gp.V2[g][(k - NH) * NH + nh];
    Wt2[gc * 512 + k] = (bf16)v;
}

// W_out [NH][NCLASS] fp32 -> WoT [NCLASS][NH] bf16 (B-operand layout), LDS tile transpose
__global__ void prep_wo(const float* __restrict__ Wo, bf16* __restrict__ WoT) {
    __shared__ float tile[32][33];
    int n0 = blockIdx.x * 32;     // 1000 blocks
    int k0 = blockIdx.y * 32;     // 8 blocks
    int tx = threadIdx.x & 31;
    int ty = threadIdx.x >> 5;    // 0..7
#pragma unroll
    for (int i = 0; i < 4; i++) {
        int k = k0 + ty + i * 8;
        tile[ty + i * 8][tx] = Wo[(size_t)k * NCLASS + n0 + tx];
    }
    __syncthreads();
#pragma unroll
    for (int i = 0; i < 4; i++) {
        int n = n0 + ty + i * 8;
        WoT[(size_t)n * NH + k0 + tx] = (bf16)tile[tx][ty + i * 8];
    }
}

// Pre-gather all embeddings: Xe[t][b][e] = (bf16)C[X[b][t]][e].
// Moves the random 512B gathers out of the serial recurrence (and out of L2's way).
// 65536 blocks x 256 threads; each thread converts 4 elements.
__global__ void prep_xe(const int* __restrict__ X, const float* __restrict__ C,
                        bf16* __restrict__ Xe) {
    size_t id = (size_t)blockIdx.x * 256 + threadIdx.x;   // 0 .. 2048*256*32-1
    int c4 = (int)(id & 31) * 4;
    int b  = (int)(id >> 5) & (B_SZ - 1);
    int t  = (int)(id >> 16);                              // 2048*32 = 2^16 per t
    int idx = X[b * T_SZ + t];
    float4 v = *(const float4*)(C + (size_t)idx * EMB + c4);
    bf16x4 hv;
    hv[0] = (bf16)v.x; hv[1] = (bf16)v.y; hv[2] = (bf16)v.z; hv[3] = (bf16)v.w;
    *(bf16x4*)(Xe + ((size_t)t * B_SZ + b) * EMB + c4) = hv;
}

// Persistent batch-parallel 2-layer LSTM, latency-hiding restructure:
//  - 64 WGs x 32 batch rows, 1024 threads (16 waves, 4 waves/SIMD).
//  - wave wv owns nh cols [wv*16, wv*16+16) across 4 gates -> per-kt: 2 A ds_reads,
//    4 B global loads, 8 MFMAs (half the old per-wave chain).
//  - A1/A2 double-buffered on timestep parity -> ONE barrier per timestep.
//    Hazard proof: all cross-wave RAW/WAR pairs are separated by the mid-step
//    barrier of the producing or consuming step (writes go to buffer p^1 while
//    readers use p; h1n write (ep1,t,buf p) vs layer-2 read (t, buf p) is the
//    one same-step dependency and it straddles the barrier).
//  - x_{t+1} streamed from pre-gathered Xe (coalesced 8KB/step) when PRE=1.
// A1 buf: [x (0..128) | h1 (128..384)] pad 392.  A2 buf: [h1n (0..256) | h2 (256..512)] pad 520.
template<int PRE>
__global__ __launch_bounds__(1024, 1) void lstm_kernel(
    const int* __restrict__ X, const float* __restrict__ C,
    const bf16* __restrict__ Wt1, const bf16* __restrict__ Wt2,
    const float* __restrict__ bi, const float* __restrict__ bf_,
    const float* __restrict__ bc, const float* __restrict__ bo,
    const bf16* __restrict__ Xe,
    bf16* __restrict__ h2out)
{
    __shared__ bf16 A1[2][32][392];   // 50176 B
    __shared__ bf16 A2[2][32][520];   // 66560 B  (total 116736 B LDS)

    const int tid  = threadIdx.x;
    const int lane = tid & 63;
    const int wv   = tid >> 6;     // 0..15: nh cols [wv*16, wv*16+16)
    const int cl   = lane & 15;    // MFMA col / A-row lane
    const int quad = lane >> 4;    // 0..3
    const int gb   = blockIdx.x * 32;

    // biases (layer2 reuses layer1 biases — reference quirk)
    const float* bp[4] = { bi, bf_, bc, bo };
    float bias[4];
#pragma unroll
    for (int g = 0; g < 4; g++) bias[g] = bp[g][wv * 16 + cl];

    // per-gate weight base pointers (inner loop = base + kt*64B immediate)
    const bf16* w1p[4];
    const bf16* w2p[4];
#pragma unroll
    for (int g = 0; g < 4; g++) {
        int gc = wv * 64 + g * 16 + cl;
        w1p[g] = Wt1 + gc * 384 + quad * 8;
        w2p[g] = Wt2 + gc * 512 + quad * 8;
    }

    // zero initial state in parity-0 buffers
    for (int i = tid; i < 8192; i += 1024) {
        int r = i >> 8, c = i & 255;
        A1[0][r][128 + c] = (bf16)0.0f;
        A2[0][r][256 + c] = (bf16)0.0f;
    }
    // x_0 into A1[0]
    {
        int r  = tid >> 5;            // 0..31
        int cc = (tid & 31) * 4;      // 0..124
        if (PRE) {
            bf16x4 hv = *(const bf16x4*)(Xe + ((size_t)0 * B_SZ + gb + r) * EMB + cc);
            *(bf16x4*)&A1[0][r][cc] = hv;
        } else {
            int idx = X[(gb + r) * T_SZ + 0];
            float4 v = *(const float4*)(C + (size_t)idx * EMB + cc);
            bf16x4 hv;
            hv[0] = (bf16)v.x; hv[1] = (bf16)v.y; hv[2] = (bf16)v.z; hv[3] = (bf16)v.w;
            *(bf16x4*)&A1[0][r][cc] = hv;
        }
    }

    f32x4 c1s[2], c2s[2];
    const f32x4 zf = { 0.0f, 0.0f, 0.0f, 0.0f };
#pragma unroll
    for (int mt = 0; mt < 2; mt++) { c1s[mt] = zf; c2s[mt] = zf; }

    __syncthreads();

    for (int t = 0; t < T_SZ; t++) {
        const int p = t & 1;

        // ---------------- layer 1: gates1 = [x_t | h1] @ Wt1 ----------------
        f32x4 acc[2][4];
#pragma unroll
        for (int mt = 0; mt < 2; mt++)
#pragma unroll
            for (int g = 0; g < 4; g++) acc[mt][g] = zf;

        {
            const bf16* a0p = &A1[p][cl][quad * 8];
            const bf16* a1p = &A1[p][16 + cl][quad * 8];
#pragma unroll
            for (int kt = 0; kt < 12; kt++) {
                bf16x8 a0 = *(const bf16x8*)(a0p + kt * 32);
                bf16x8 a1 = *(const bf16x8*)(a1p + kt * 32);
#pragma unroll
                for (int g = 0; g < 4; g++) {
                    bf16x8 b = *(const bf16x8*)(w1p[g] + kt * 32);
                    acc[0][g] = __builtin_amdgcn_mfma_f32_16x16x32_bf16(a0, b, acc[0][g], 0, 0, 0);
                    acc[1][g] = __builtin_amdgcn_mfma_f32_16x16x32_bf16(a1, b, acc[1][g], 0, 0, 0);
                }
            }
        }

        // epilogue 1: c1,h1n -> A1[p^1].h1 and A2[p].h1n   (writes race-free: see header)
#pragma unroll
        for (int mt = 0; mt < 2; mt++)
#pragma unroll
            for (int r = 0; r < 4; r++) {
                float iv = sigf(acc[mt][0][r] + bias[0]);
                float fv = sigf(acc[mt][1][r] + bias[1]);
                float gv = tanhfast(acc[mt][2][r] + bias[2]);
                float ov = sigf(acc[mt][3][r] + bias[3]);
                float c  = c1s[mt][r] * fv + iv * gv;
                c1s[mt][r] = c;
                float h  = ov * tanhfast(c);
                int row = mt * 16 + quad * 4 + r;
                int col = wv * 16 + cl;
                bf16 hb = (bf16)h;
                A1[p ^ 1][row][128 + col] = hb;
                A2[p][row][col]           = hb;
            }

        // stream x_{t+1} into A1[p^1].x
        if (t + 1 < T_SZ) {
            int r  = tid >> 5;
            int cc = (tid & 31) * 4;
            if (PRE) {
                bf16x4 hv = *(const bf16x4*)(Xe + ((size_t)(t + 1) * B_SZ + gb + r) * EMB + cc);
                *(bf16x4*)&A1[p ^ 1][r][cc] = hv;
            } else {
                int idx = X[(gb + r) * T_SZ + (t + 1)];
                float4 v = *(const float4*)(C + (size_t)idx * EMB + cc);
                bf16x4 hv;
                hv[0] = (bf16)v.x; hv[1] = (bf16)v.y; hv[2] = (bf16)v.z; hv[3] = (bf16)v.w;
                *(bf16x4*)&A1[p ^ 1][r][cc] = hv;
            }
        }

        __syncthreads();   // the ONLY barrier per step: h1n(t) visible for layer 2

        // ---------------- layer 2: gates2 = [h1n | h2] @ Wt2 ----------------
#pragma unroll
        for (int mt = 0; mt < 2; mt++)
#pragma unroll
            for (int g = 0; g < 4; g++) acc[mt][g] = zf;

        {
            const bf16* a0p = &A2[p][cl][quad * 8];
            const bf16* a1p = &A2[p][16 + cl][quad * 8];
#pragma unroll
            for (int kt = 0; kt < 16; kt++) {
                bf16x8 a0 = *(const bf16x8*)(a0p + kt * 32);
                bf16x8 a1 = *(const bf16x8*)(a1p + kt * 32);
#pragma unroll
                for (int g = 0; g < 4; g++) {
                    bf16x8 b = *(const bf16x8*)(w2p[g] + kt * 32);
                    acc[0][g] = __builtin_amdgcn_mfma_f32_16x16x32_bf16(a0, b, acc[0][g], 0, 0, 0);
                    acc[1][g] = __builtin_amdgcn_mfma_f32_16x16x32_bf16(a1, b, acc[1][g], 0, 0, 0);
                }
            }
        }

        // epilogue 2: c2,h2n -> A2[p^1].h2 (read only after next step's barrier)
#pragma unroll
        for (int mt = 0; mt < 2; mt++)
#pragma unroll
            for (int r = 0; r < 4; r++) {
                float iv = sigf(acc[mt][0][r] + bias[0]);
                float fv = sigf(acc[mt][1][r] + bias[1]);
                float gv = tanhfast(acc[mt][2][r] + bias[2]);
                float ov = sigf(acc[mt][3][r] + bias[3]);
                float c  = c2s[mt][r] * fv + iv * gv;
                c2s[mt][r] = c;
                float h  = ov * tanhfast(c);
                int row = mt * 16 + quad * 4 + r;
                int col = wv * 16 + cl;
                A2[p ^ 1][row][256 + col] = (bf16)h;
            }
        // no end-of-step barrier: next MFMA1 reads A1[p^1], whose writers all
        // preceded THIS step's barrier; A2[p^1].h2 is read only after barrier(t+1).
    }

    __syncthreads();
    // final h2 lives in A2[(255&1)^1] = A2[0]
    for (int i = tid; i < 8192; i += 1024) {
        int r = i >> 8, c = i & 255;
        h2out[(size_t)(gb + r) * NH + c] = A2[0][r][256 + c];
    }
}

// out[2048][32000] = h2 @ W_out + b_out.  Tile: WG 64(M) x 64(N), wave = 16(M) x 64(N).
__global__ __launch_bounds__(256, 1) void out_gemm(
    const bf16* __restrict__ h2, const bf16* __restrict__ WoT,
    const float* __restrict__ bout, float* __restrict__ out)
{
    const int tid  = threadIdx.x;
    const int lane = tid & 63;
    const int wv   = tid >> 6;    // 0..3
    const int cl   = lane & 15;
    const int quad = lane >> 4;
    const int nb   = blockIdx.x;  // 0..499
    const int mb   = blockIdx.y;  // 0..31
    const int mbase = mb * 64 + wv * 16;
    const int nbase = nb * 64;

    f32x4 acc[4];
    const f32x4 zf = { 0.0f, 0.0f, 0.0f, 0.0f };
#pragma unroll
    for (int nt = 0; nt < 4; nt++) acc[nt] = zf;

#pragma unroll
    for (int kt = 0; kt < 8; kt++) {
        bf16x8 a = *(const bf16x8*)(h2 + (size_t)(mbase + cl) * NH + kt * 32 + quad * 8);
#pragma unroll
        for (int nt = 0; nt < 4; nt++) {
            bf16x8 b = *(const bf16x8*)(WoT + (size_t)(nbase + nt * 16 + cl) * NH + kt * 32 + quad * 8);
            acc[nt] = __builtin_amdgcn_mfma_f32_16x16x32_bf16(a, b, acc[nt], 0, 0, 0);
        }
    }
#pragma unroll
    for (int nt = 0; nt < 4; nt++) {
        int col = nbase + nt * 16 + cl;
        float bv = bout[col];
#pragma unroll
        for (int r = 0; r < 4; r++) {
            int row = mbase + quad * 4 + r;
            out[(size_t)row * NCLASS + col] = acc[nt][r] + bv;
        }
    }
}

extern "C" void kernel_launch(void* const* d_in, const int* in_sizes, int n_in,
                              void* d_out, int out_size, void* d_ws, size_t ws_size,
                              hipStream_t stream) {
    const int*   X  = (const int*)d_in[0];
    const float* C  = (const float*)d_in[1];
    GatePtrs gp;
    for (int g = 0; g < 4; g++) {          // gate order i,f,c,o -> input groups at 2+5g
        int base = 2 + 5 * g;
        gp.U1[g] = (const float*)d_in[base + 0];
        gp.V1[g] = (const float*)d_in[base + 1];
        gp.U2[g] = (const float*)d_in[base + 2];
        gp.V2[g] = (const float*)d_in[base + 3];
    }
    const float* bi   = (const float*)d_in[6];
    const float* bf_  = (const float*)d_in[11];
    const float* bc   = (const float*)d_in[16];
    const float* bo   = (const float*)d_in[21];
    const float* Wo   = (const float*)d_in[22];
    const float* bout = (const float*)d_in[23];
    float* out = (float*)d_out;

    char* ws = (char*)d_ws;
    bf16* Wt1 = (bf16*)(ws);                                    // 1024*384*2 = 786432
    bf16* Wt2 = (bf16*)(ws + 786432);                           // 1024*512*2 = 1048576
    bf16* WoT = (bf16*)(ws + 786432 + 1048576);                 // 32000*256*2 = 16384000
    bf16* h2w = (bf16*)(ws + 786432 + 1048576 + 16384000);      // 2048*256*2  = 1048576
    bf16* Xe  = (bf16*)(ws + 786432 + 1048576 + 16384000 + 1048576);  // 256*2048*128*2 = 134217728
    const size_t WS_NEED_XE = 786432ull + 1048576 + 16384000 + 1048576 + 134217728;

    prep_w1<<<dim3(1024), dim3(384), 0, stream>>>(gp, Wt1);
    prep_w2<<<dim3(1024), dim3(512), 0, stream>>>(gp, Wt2);
    prep_wo<<<dim3(1000, 8), dim3(256), 0, stream>>>(Wo, WoT);

    if (ws_size >= WS_NEED_XE) {
        prep_xe<<<dim3(65536), dim3(256), 0, stream>>>(X, C, Xe);
        lstm_kernel<1><<<dim3(64), dim3(1024), 0, stream>>>(X, C, Wt1, Wt2, bi, bf_, bc, bo, Xe, h2w);
    } else {
        lstm_kernel<0><<<dim3(64), dim3(1024), 0, stream>>>(X, C, Wt1, Wt2, bi, bf_, bc, bo, Xe, h2w);
    }

    out_gemm<<<dim3(500, 32), dim3(256), 0, stream>>>(h2w, WoT, bout, out);
}